// Round 2
// baseline (1204.704 us; speedup 1.0000x reference)
//
#include <hip/hip_runtime.h>
#include <cstdint>
#include <cstddef>

// ---------------- problem constants ----------------
constexpr int kB   = 64;      // graphs
constexpr int kN   = 1000;    // nodes per graph
constexpr int kF   = 64;      // node features
constexpr int kE   = 32000;   // edges
constexpr int kIn  = 64000;   // N*F flattened
constexpr int kHid = 512;
constexpr int kLat = 128;
constexpr float kSlope = 0.01f;

constexpr int KCHUNK = 512;            // split-K chunk for encoder
constexpr int NCHUNK = kIn / KCHUNK;   // 125

// ---------------- workspace layout (bytes) ----------------
constexpr size_t OFF_OFFS   = 0;                                   // int[1001]
constexpr size_t OFF_DEGF   = 4096;                                // float[1000]
constexpr size_t OFF_INVD   = 8192;                                // float[1000]
constexpr size_t OFF_BUCKET = 12288;                               // int[32000]
constexpr size_t OFF_XS     = 140288;                              // float[64*64000]
constexpr size_t OFF_HE     = OFF_XS  + (size_t)kB * kIn  * 4;     // float[64*512]
constexpr size_t OFF_HDT    = OFF_HE  + (size_t)kB * kHid * 4;     // float[512*64]
constexpr size_t OFF_PART   = OFF_HDT + (size_t)kHid * kB * 4;     // float[125*64*512]
constexpr size_t WS_PART    = OFF_PART + (size_t)NCHUNK * kB * kHid * 4;

// ---------------- fused graph preprocessing (single block) ----------------
// histogram -> inclusive scan -> CSR fill, all via LDS. One dispatch.
__global__ __launch_bounds__(1024) void gnn_k_pre(
    const int* __restrict__ ei, int* __restrict__ offs, int* __restrict__ bucket,
    float* __restrict__ degf, float* __restrict__ invd) {
    __shared__ int s_deg[kN];
    __shared__ int s_scan[1024];
    __shared__ int s_cur[kN];
    int t = threadIdx.x;
    if (t < kN) s_deg[t] = 0;
    __syncthreads();
    for (int e = t; e < kE; e += 1024) atomicAdd(&s_deg[ei[kE + e]], 1);
    __syncthreads();
    int v = (t < kN) ? s_deg[t] : 0;
    s_scan[t] = v;
    __syncthreads();
    for (int d = 1; d < 1024; d <<= 1) {
        int add = (t >= d) ? s_scan[t - d] : 0;
        __syncthreads();
        s_scan[t] += add;
        __syncthreads();
    }
    if (t < kN) {
        int excl = s_scan[t] - v;      // exclusive prefix
        offs[t]  = excl;
        s_cur[t] = excl;
        degf[t]  = (float)v;
        invd[t]  = 1.0f / fmaxf((float)v, 1.0f);
    }
    if (t == kN - 1) offs[kN] = s_scan[t];
    __syncthreads();
    for (int e = t; e < kE; e += 1024) {
        int d = ei[kE + e];
        int pos = atomicAdd(&s_cur[d], 1);
        bucket[pos] = ei[e];           // src
    }
}

// ---------------- GeneralConv: aggregate + linear + skip + LeakyReLU ----------------
// 256 threads = 4 waves = 4 nodes of one graph. Wave-local matmul via readlane
// broadcast (no LDS, no barrier). grid = B * N/4, b-major for L2 locality.
__global__ __launch_bounds__(256) void gnn_k_conv(
    const float* __restrict__ x, const float* __restrict__ Wm,
    const float* __restrict__ bm, const int* __restrict__ offs,
    const int* __restrict__ bucket, const float* __restrict__ degf,
    const float* __restrict__ invd, float* __restrict__ xs) {
    int blk  = blockIdx.x;
    int b    = blk / (kN / 4);
    int ng   = blk - b * (kN / 4);
    int wave = threadIdx.x >> 6;
    int f    = threadIdx.x & 63;
    int n    = ng * 4 + wave;
    const float* xb = x + (size_t)b * kIn;
    int beg = offs[n], end = offs[n + 1];
    float a0 = 0.f, a1 = 0.f;
    int i = beg;
    for (; i + 2 <= end; i += 2) {        // 2-way ILP on the gather
        int s0 = bucket[i], s1 = bucket[i + 1];
        a0 += xb[s0 * kF + f];
        a1 += xb[s1 * kF + f];
    }
    if (i < end) a0 += xb[bucket[i] * kF + f];
    float acc = a0 + a1;
    // dot[f] = sum_ff acc(lane ff) * Wm[ff][f]; 4 partial chains for FMA ILP
    float d0 = 0.f, d1 = 0.f, d2 = 0.f, d3 = 0.f;
    #pragma unroll
    for (int ff = 0; ff < kF; ff += 4) {
        d0 = fmaf(__shfl(acc, ff    ), Wm[(ff    ) * kF + f], d0);
        d1 = fmaf(__shfl(acc, ff + 1), Wm[(ff + 1) * kF + f], d1);
        d2 = fmaf(__shfl(acc, ff + 2), Wm[(ff + 2) * kF + f], d2);
        d3 = fmaf(__shfl(acc, ff + 3), Wm[(ff + 3) * kF + f], d3);
    }
    float dot = (d0 + d1) + (d2 + d3);
    float dg  = degf[n];
    float val = (dot + dg * bm[f]) * invd[n];
    float hv  = val + xb[n * kF + f];          // identity skip
    hv = hv >= 0.f ? hv : kSlope * hv;         // LeakyReLU
    xs[(size_t)b * kIn + n * kF + f] = hv;
}

// ---------------- Encoder GEMM: he_pre = xs[64,64000] @ W_e1[64000,512] (split-K) ----
// grid (NCHUNK, 2), block 256. Thread owns one column; acc over 64 batch rows.
// xs loads are wave-uniform -> scalar (s_load) path; W loads coalesced vector.
template <bool ATOMIC>
__global__ __launch_bounds__(256) void gnn_k_enc(
    const float* __restrict__ xs, const float* __restrict__ We1,
    float* __restrict__ out) {
    int c   = blockIdx.x;
    int col = blockIdx.y * 256 + threadIdx.x;
    int k0  = c * KCHUNK;
    float acc[kB];
    #pragma unroll
    for (int m = 0; m < kB; ++m) acc[m] = 0.f;
    const float* wp = We1 + (size_t)k0 * kHid + col;
    const float* xk = xs + k0;
    for (int k = 0; k < KCHUNK; k += 4) {
        float w0 = wp[0];
        float w1 = wp[kHid];
        float w2 = wp[2 * kHid];
        float w3 = wp[3 * kHid];
        wp += 4 * kHid;
        const float* xr = xk + k;
        #pragma unroll
        for (int m = 0; m < kB; ++m) {
            const float* xm = xr + (size_t)m * kIn;   // wave-uniform
            acc[m] = fmaf(xm[0], w0, fmaf(xm[1], w1, fmaf(xm[2], w2, fmaf(xm[3], w3, acc[m]))));
        }
    }
    if (ATOMIC) {
        #pragma unroll
        for (int m = 0; m < kB; ++m) atomicAdd(&out[(size_t)m * kHid + col], acc[m]);
    } else {
        float* pp = out + ((size_t)c * kB) * kHid + col;
        #pragma unroll
        for (int m = 0; m < kB; ++m) pp[(size_t)m * kHid] = acc[m];
    }
}

__global__ void gnn_k_encred(const float* __restrict__ part,
                             const float* __restrict__ be1, float* __restrict__ he) {
    int m = blockIdx.x;      // 64 blocks
    int n = threadIdx.x;     // 512 threads
    float s = 0.f;
    for (int c = 0; c < NCHUNK; ++c) s += part[((size_t)c * kB + m) * kHid + n];
    s += be1[n];
    he[(size_t)m * kHid + n] = s > 0.f ? s : 0.f;
}

__global__ void gnn_k_hefin(float* __restrict__ he, const float* __restrict__ be1) {
    int i = blockIdx.x * 256 + threadIdx.x;
    if (i < kB * kHid) {
        float v = he[i] + be1[i & 511];
        he[i] = v > 0.f ? v : 0.f;
    }
}

// ---------------- fused latent + decoder layer 1 ----------------
// block b: threads 0..127 compute mean/log_var/z (into LDS); all 512 then
// compute hd^T column. Saves a dispatch + a global round-trip for z.
__global__ __launch_bounds__(512) void gnn_k_latdec1(
    const float* __restrict__ he, const float* __restrict__ Wmean,
    const float* __restrict__ bmean, const float* __restrict__ Wlv,
    const float* __restrict__ blv, const float* __restrict__ eps,
    const float* __restrict__ Wd1, const float* __restrict__ bd1,
    float* __restrict__ outMean, float* __restrict__ outLv,
    float* __restrict__ hdT) {
    int b = blockIdx.x;
    int t = threadIdx.x;
    __shared__ float s_he[kHid];
    __shared__ float s_z[kLat];
    s_he[t] = he[(size_t)b * kHid + t];
    __syncthreads();
    if (t < kLat) {
        float dm = bmean[t], dv = blv[t];
        float dm1 = 0.f, dv1 = 0.f;
        #pragma unroll 4
        for (int k = 0; k < kHid; k += 2) {
            float h0 = s_he[k], h1 = s_he[k + 1];
            dm  = fmaf(h0, Wmean[(size_t)k * kLat + t], dm);
            dm1 = fmaf(h1, Wmean[(size_t)(k + 1) * kLat + t], dm1);
            dv  = fmaf(h0, Wlv[(size_t)k * kLat + t], dv);
            dv1 = fmaf(h1, Wlv[(size_t)(k + 1) * kLat + t], dv1);
        }
        dm += dm1; dv += dv1;
        outMean[b * kLat + t] = dm;
        outLv[b * kLat + t]   = dv;
        s_z[t] = fmaf(expf(0.5f * dv), eps[b * kLat + t], dm);
    }
    __syncthreads();
    float acc = bd1[t];
    float acc1 = 0.f;
    #pragma unroll 4
    for (int k = 0; k < kLat; k += 2) {
        acc  = fmaf(s_z[k],     Wd1[(size_t)k * kHid + t], acc);
        acc1 = fmaf(s_z[k + 1], Wd1[(size_t)(k + 1) * kHid + t], acc1);
    }
    acc += acc1;
    hdT[(size_t)t * kB + b] = fmaxf(acc, 0.f);   // ReLU, transposed store
}

// ---------------- decoder GEMM: x_hat = sigmoid(hd @ W_d2 + b_d2) -------------------
// grid 250, block 256: thread owns one output column, acc over 64 rows.
__global__ __launch_bounds__(256) void gnn_k_dec2(
    const float* __restrict__ hdT, const float* __restrict__ Wd2,
    const float* __restrict__ bd2, float* __restrict__ out) {
    int col = blockIdx.x * 256 + threadIdx.x;
    float acc[kB];
    #pragma unroll
    for (int m = 0; m < kB; ++m) acc[m] = 0.f;
    const float* wp = Wd2 + col;
    for (int k = 0; k < kHid; k += 2) {
        float w0 = wp[(size_t)k * kIn];
        float w1 = wp[(size_t)(k + 1) * kIn];
        const float* h0 = hdT + k * kB;        // wave-uniform, contiguous -> s_load
        const float* h1 = hdT + (k + 1) * kB;
        #pragma unroll
        for (int m = 0; m < kB; ++m)
            acc[m] = fmaf(h0[m], w0, fmaf(h1[m], w1, acc[m]));
    }
    float bb = bd2[col];
    #pragma unroll
    for (int m = 0; m < kB; ++m) {
        float v = acc[m] + bb;
        out[(size_t)m * kIn + col] = 1.f / (1.f + expf(-v));
    }
}

// ---------------- launcher ----------------
extern "C" void kernel_launch(void* const* d_in, const int* in_sizes, int n_in,
                              void* d_out, int out_size, void* d_ws, size_t ws_size,
                              hipStream_t stream) {
    const float* x     = (const float*)d_in[0];
    const int*   ei    = (const int*)d_in[1];
    const float* eps   = (const float*)d_in[2];
    const float* Wm    = (const float*)d_in[3];
    const float* bm    = (const float*)d_in[4];
    const float* We1   = (const float*)d_in[5];
    const float* be1   = (const float*)d_in[6];
    const float* Wmean = (const float*)d_in[7];
    const float* bmean = (const float*)d_in[8];
    const float* Wlv   = (const float*)d_in[9];
    const float* blv   = (const float*)d_in[10];
    const float* Wd1   = (const float*)d_in[11];
    const float* bd1   = (const float*)d_in[12];
    const float* Wd2   = (const float*)d_in[13];
    const float* bd2   = (const float*)d_in[14];
    float* out = (float*)d_out;

    char* ws = (char*)d_ws;
    int*   offs   = (int*)(ws + OFF_OFFS);
    float* degf   = (float*)(ws + OFF_DEGF);
    float* invd   = (float*)(ws + OFF_INVD);
    int*   bucket = (int*)(ws + OFF_BUCKET);
    float* xs     = (float*)(ws + OFF_XS);
    float* he     = (float*)(ws + OFF_HE);
    float* hdT    = (float*)(ws + OFF_HDT);
    float* part   = (float*)(ws + OFF_PART);

    float* outMean = out + (size_t)kB * kIn;
    float* outLv   = outMean + (size_t)kB * kLat;

    // fused preprocessing (edge_index restored before every call; ws re-poisoned)
    gnn_k_pre<<<1, 1024, 0, stream>>>(ei, offs, bucket, degf, invd);

    // conv + skip + leaky
    gnn_k_conv<<<kB * (kN / 4), 256, 0, stream>>>(x, Wm, bm, offs, bucket, degf, invd, xs);

    // encoder GEMM (split-K, deterministic partials if ws allows)
    if (ws_size >= WS_PART) {
        gnn_k_enc<false><<<dim3(NCHUNK, 2), 256, 0, stream>>>(xs, We1, part);
        gnn_k_encred<<<kB, kHid, 0, stream>>>(part, be1, he);
    } else {
        hipMemsetAsync(he, 0, (size_t)kB * kHid * 4, stream);
        gnn_k_enc<true><<<dim3(NCHUNK, 2), 256, 0, stream>>>(xs, We1, he);
        gnn_k_hefin<<<(kB * kHid + 255) / 256, 256, 0, stream>>>(he, be1);
    }

    // fused latent + decoder layer 1
    gnn_k_latdec1<<<kB, kHid, 0, stream>>>(he, Wmean, bmean, Wlv, blv, eps,
                                           Wd1, bd1, outMean, outLv, hdT);

    // decoder GEMM + sigmoid
    gnn_k_dec2<<<kIn / 256, 256, 0, stream>>>(hdT, Wd2, bd2, out);
}

// Round 4
// 869.088 us; speedup vs baseline: 1.3862x; 1.3862x over previous
//
#include <hip/hip_runtime.h>
#include <cstdint>
#include <cstddef>

// ---------------- problem constants ----------------
constexpr int kB   = 64;      // graphs
constexpr int kN   = 1000;    // nodes per graph
constexpr int kF   = 64;      // node features
constexpr int kE   = 32000;   // edges
constexpr int kIn  = 64000;   // N*F flattened
constexpr int kHid = 512;
constexpr int kLat = 128;
constexpr float kSlope = 0.01f;

constexpr int KC  = 256;           // encoder k-chunk
constexpr int NKC = kIn / KC;      // 250 chunks

// ---------------- workspace layout (bytes) ----------------
constexpr size_t OFF_OFFS   = 0;                                   // int[1001]
constexpr size_t OFF_DEGF   = 4096;                                // float[1000]
constexpr size_t OFF_INVD   = 8192;                                // float[1000]
constexpr size_t OFF_BUCKET = 12288;                               // int[32000]
constexpr size_t OFF_XS     = 140288;                              // float[64*64000]
constexpr size_t OFF_HE     = OFF_XS  + (size_t)kB * kIn  * 4;     // float[64*512]
constexpr size_t OFF_HDT    = OFF_HE  + (size_t)kB * kHid * 4;     // float[512*64]
constexpr size_t OFF_PART   = OFF_HDT + (size_t)kHid * kB * 4;     // float[250*64*512]
constexpr size_t WS_NEED    = OFF_PART + (size_t)NKC * kB * kHid * 4;

// ---------------- fused graph preprocessing (single block) ----------------
__global__ __launch_bounds__(1024) void gnn_k_pre(
    const int* __restrict__ ei, int* __restrict__ offs, int* __restrict__ bucket,
    float* __restrict__ degf, float* __restrict__ invd) {
    __shared__ int s_deg[kN];
    __shared__ int s_scan[1024];
    __shared__ int s_cur[kN];
    int t = threadIdx.x;
    if (t < kN) s_deg[t] = 0;
    __syncthreads();
    for (int e = t; e < kE; e += 1024) atomicAdd(&s_deg[ei[kE + e]], 1);
    __syncthreads();
    int v = (t < kN) ? s_deg[t] : 0;
    s_scan[t] = v;
    __syncthreads();
    for (int d = 1; d < 1024; d <<= 1) {
        int add = (t >= d) ? s_scan[t - d] : 0;
        __syncthreads();
        s_scan[t] += add;
        __syncthreads();
    }
    if (t < kN) {
        int excl = s_scan[t] - v;
        offs[t]  = excl;
        s_cur[t] = excl;
        degf[t]  = (float)v;
        invd[t]  = 1.0f / fmaxf((float)v, 1.0f);
    }
    if (t == kN - 1) offs[kN] = s_scan[t];
    __syncthreads();
    for (int e = t; e < kE; e += 1024) {
        int d = ei[kE + e];
        int pos = atomicAdd(&s_cur[d], 1);
        bucket[pos] = ei[e];           // src
    }
}

// ---------------- GeneralConv: aggregate + linear + skip + LeakyReLU ----------------
// 256 threads = 4 waves = 4 nodes. Wave matmul via readlane broadcast.
__global__ __launch_bounds__(256) void gnn_k_conv(
    const float* __restrict__ x, const float* __restrict__ Wm,
    const float* __restrict__ bm, const int* __restrict__ offs,
    const int* __restrict__ bucket, const float* __restrict__ degf,
    const float* __restrict__ invd, float* __restrict__ xs) {
    int blk  = blockIdx.x;
    int b    = blk / (kN / 4);
    int ng   = blk - b * (kN / 4);
    int wave = threadIdx.x >> 6;
    int f    = threadIdx.x & 63;
    int n    = ng * 4 + wave;
    const float* xb = x + (size_t)b * kIn;
    int beg = offs[n], end = offs[n + 1];
    float a0 = 0.f, a1 = 0.f;
    int i = beg;
    for (; i + 2 <= end; i += 2) {
        int s0 = bucket[i], s1 = bucket[i + 1];
        a0 += xb[s0 * kF + f];
        a1 += xb[s1 * kF + f];
    }
    if (i < end) a0 += xb[bucket[i] * kF + f];
    float acc = a0 + a1;
    float d0 = 0.f, d1 = 0.f, d2 = 0.f, d3 = 0.f;
    #pragma unroll
    for (int ff = 0; ff < kF; ff += 4) {
        d0 = fmaf(__shfl(acc, ff    ), Wm[(ff    ) * kF + f], d0);
        d1 = fmaf(__shfl(acc, ff + 1), Wm[(ff + 1) * kF + f], d1);
        d2 = fmaf(__shfl(acc, ff + 2), Wm[(ff + 2) * kF + f], d2);
        d3 = fmaf(__shfl(acc, ff + 3), Wm[(ff + 3) * kF + f], d3);
    }
    float dot = (d0 + d1) + (d2 + d3);
    float dg  = degf[n];
    float val = (dot + dg * bm[f]) * invd[n];
    float hv  = val + xb[n * kF + f];
    hv = hv >= 0.f ? hv : kSlope * hv;
    xs[(size_t)b * kIn + n * kF + f] = hv;
}

// ---------------- Encoder GEMM (LDS-staged, register-tiled, split-K) ----------------
// grid (NKC, 2), block 256. Block: [64m x 256n] over 256 k. Thread: 16m x 4n.
// LDS x-reads are wave-broadcast b128 (conflict-free); W reads coalesced float4.
template <bool ATOMIC>
__global__ __launch_bounds__(256) void gnn_k_enc(
    const float* __restrict__ xs, const float* __restrict__ We1,
    float* __restrict__ out) {
    int c  = blockIdx.x;
    int by = blockIdx.y;
    int t  = threadIdx.x;
    int nl = t & 63;
    int mg = t >> 6;
    int k0 = c * KC;
    int cb = by * 256 + nl * 4;
    int m0 = mg * 16;

    __shared__ float s_x[kB][KC];          // 64 KB
    const float4* xs4 = (const float4*)xs;
    #pragma unroll
    for (int i = t; i < kB * (KC / 4); i += 256) {
        int m  = i >> 6;                   // KC/4 = 64 float4 per row
        int jw = i & 63;
        *(float4*)&s_x[m][jw * 4] = xs4[(size_t)m * (kIn / 4) + (k0 >> 2) + jw];
    }
    __syncthreads();

    float acc[16][4];
    #pragma unroll
    for (int mm = 0; mm < 16; ++mm)
        #pragma unroll
        for (int j = 0; j < 4; ++j) acc[mm][j] = 0.f;

    const float* wbase = We1 + (size_t)k0 * kHid + cb;
    for (int kk = 0; kk < KC; kk += 4) {
        const float* wk = wbase + (size_t)kk * kHid;
        float4 w0 = *(const float4*)(wk);
        float4 w1 = *(const float4*)(wk + kHid);
        float4 w2 = *(const float4*)(wk + 2 * kHid);
        float4 w3 = *(const float4*)(wk + 3 * kHid);
        #pragma unroll
        for (int mm = 0; mm < 16; ++mm) {
            float4 xv = *(const float4*)&s_x[m0 + mm][kk];   // wave-broadcast
            acc[mm][0] = fmaf(xv.x, w0.x, fmaf(xv.y, w1.x, fmaf(xv.z, w2.x, fmaf(xv.w, w3.x, acc[mm][0]))));
            acc[mm][1] = fmaf(xv.x, w0.y, fmaf(xv.y, w1.y, fmaf(xv.z, w2.y, fmaf(xv.w, w3.y, acc[mm][1]))));
            acc[mm][2] = fmaf(xv.x, w0.z, fmaf(xv.y, w1.z, fmaf(xv.z, w2.z, fmaf(xv.w, w3.z, acc[mm][2]))));
            acc[mm][3] = fmaf(xv.x, w0.w, fmaf(xv.y, w1.w, fmaf(xv.z, w2.w, fmaf(xv.w, w3.w, acc[mm][3]))));
        }
    }

    if (ATOMIC) {
        #pragma unroll
        for (int mm = 0; mm < 16; ++mm)
            #pragma unroll
            for (int j = 0; j < 4; ++j)
                atomicAdd(&out[(size_t)(m0 + mm) * kHid + cb + j], acc[mm][j]);
    } else {
        #pragma unroll
        for (int mm = 0; mm < 16; ++mm) {
            float4 v = make_float4(acc[mm][0], acc[mm][1], acc[mm][2], acc[mm][3]);
            *(float4*)&out[((size_t)c * kB + m0 + mm) * kHid + cb] = v;
        }
    }
}

// reduce partials + bias + ReLU
__global__ __launch_bounds__(256) void gnn_k_encred(
    const float* __restrict__ part, const float* __restrict__ be1,
    float* __restrict__ he) {
    int id = blockIdx.x * 256 + threadIdx.x;   // 32768
    int n = id & 511, m = id >> 9;
    float s0 = 0.f, s1 = 0.f, s2 = 0.f, s3 = 0.f;
    const float* p = part + (size_t)m * kHid + n;
    #pragma unroll 2
    for (int c = 0; c < NKC; c += 4) {
        s0 += p[(size_t)(c    ) * kB * kHid];
        s1 += p[(size_t)(c + 1) * kB * kHid];
        s2 += p[(size_t)(c + 2) * kB * kHid];
        s3 += p[(size_t)(c + 3) * kB * kHid];
    }
    float s = (s0 + s1) + (s2 + s3) + be1[n];
    he[id] = fmaxf(s, 0.f);
}

__global__ void gnn_k_hefin(float* __restrict__ he, const float* __restrict__ be1) {
    int i = blockIdx.x * 256 + threadIdx.x;
    if (i < kB * kHid) {
        float v = he[i] + be1[i & 511];
        he[i] = v > 0.f ? v : 0.f;
    }
}

// ---------------- fused latent + decoder layer 1 ----------------
__global__ __launch_bounds__(512) void gnn_k_latdec1(
    const float* __restrict__ he, const float* __restrict__ Wmean,
    const float* __restrict__ bmean, const float* __restrict__ Wlv,
    const float* __restrict__ blv, const float* __restrict__ eps,
    const float* __restrict__ Wd1, const float* __restrict__ bd1,
    float* __restrict__ outMean, float* __restrict__ outLv,
    float* __restrict__ hdT) {
    int b = blockIdx.x;
    int t = threadIdx.x;
    __shared__ float s_he[kHid];
    __shared__ float s_z[kLat];
    s_he[t] = he[(size_t)b * kHid + t];
    __syncthreads();
    if (t < kLat) {
        float dm = bmean[t], dv = blv[t];
        float dm1 = 0.f, dv1 = 0.f;
        #pragma unroll 4
        for (int k = 0; k < kHid; k += 2) {
            float h0 = s_he[k], h1 = s_he[k + 1];
            dm  = fmaf(h0, Wmean[(size_t)k * kLat + t], dm);
            dm1 = fmaf(h1, Wmean[(size_t)(k + 1) * kLat + t], dm1);
            dv  = fmaf(h0, Wlv[(size_t)k * kLat + t], dv);
            dv1 = fmaf(h1, Wlv[(size_t)(k + 1) * kLat + t], dv1);
        }
        dm += dm1; dv += dv1;
        outMean[b * kLat + t] = dm;
        outLv[b * kLat + t]   = dv;
        s_z[t] = fmaf(expf(0.5f * dv), eps[b * kLat + t], dm);
    }
    __syncthreads();
    float acc = bd1[t];
    float acc1 = 0.f;
    #pragma unroll 4
    for (int k = 0; k < kLat; k += 2) {
        acc  = fmaf(s_z[k],     Wd1[(size_t)k * kHid + t], acc);
        acc1 = fmaf(s_z[k + 1], Wd1[(size_t)(k + 1) * kHid + t], acc1);
    }
    acc += acc1;
    hdT[(size_t)t * kB + b] = fmaxf(acc, 0.f);   // transposed: hdT[k][m]
}

// ---------------- decoder GEMM: lane=m formulation ----------------
// wave w handles cols [w*32, w*32+32), lane = batch row m.
// hdT[k][0..63] read coalesced (256B/wave); W reads wave-uniform float4.
__global__ __launch_bounds__(256) void gnn_k_dec2(
    const float* __restrict__ hdT, const float* __restrict__ Wd2,
    const float* __restrict__ bd2, float* __restrict__ out) {
    int t = threadIdx.x;
    int lane = t & 63;
    int w = (blockIdx.x << 2) + (t >> 6);
    int c0 = w * 32;
    float acc[32];
    #pragma unroll
    for (int j = 0; j < 32; ++j) acc[j] = 0.f;
    for (int k = 0; k < kHid; k += 2) {
        float h0 = hdT[k * kB + lane];
        float h1 = hdT[(k + 1) * kB + lane];
        const float4* wr0 = (const float4*)(Wd2 + (size_t)k * kIn + c0);
        const float4* wr1 = (const float4*)(Wd2 + (size_t)(k + 1) * kIn + c0);
        #pragma unroll
        for (int jq = 0; jq < 8; ++jq) {
            float4 a = wr0[jq];
            float4 b = wr1[jq];
            acc[jq * 4 + 0] = fmaf(h1, b.x, fmaf(h0, a.x, acc[jq * 4 + 0]));
            acc[jq * 4 + 1] = fmaf(h1, b.y, fmaf(h0, a.y, acc[jq * 4 + 1]));
            acc[jq * 4 + 2] = fmaf(h1, b.z, fmaf(h0, a.z, acc[jq * 4 + 2]));
            acc[jq * 4 + 3] = fmaf(h1, b.w, fmaf(h0, a.w, acc[jq * 4 + 3]));
        }
    }
    float* op = out + (size_t)lane * kIn + c0;
    #pragma unroll
    for (int jq = 0; jq < 8; ++jq) {
        float4 bb = *(const float4*)(bd2 + c0 + jq * 4);
        float4 v;
        v.x = 1.f / (1.f + expf(-(acc[jq * 4 + 0] + bb.x)));
        v.y = 1.f / (1.f + expf(-(acc[jq * 4 + 1] + bb.y)));
        v.z = 1.f / (1.f + expf(-(acc[jq * 4 + 2] + bb.z)));
        v.w = 1.f / (1.f + expf(-(acc[jq * 4 + 3] + bb.w)));
        *(float4*)(op + jq * 4) = v;
    }
}

// ---------------- launcher ----------------
extern "C" void kernel_launch(void* const* d_in, const int* in_sizes, int n_in,
                              void* d_out, int out_size, void* d_ws, size_t ws_size,
                              hipStream_t stream) {
    const float* x     = (const float*)d_in[0];
    const int*   ei    = (const int*)d_in[1];
    const float* eps   = (const float*)d_in[2];
    const float* Wm    = (const float*)d_in[3];
    const float* bm    = (const float*)d_in[4];
    const float* We1   = (const float*)d_in[5];
    const float* be1   = (const float*)d_in[6];
    const float* Wmean = (const float*)d_in[7];
    const float* bmean = (const float*)d_in[8];
    const float* Wlv   = (const float*)d_in[9];
    const float* blv   = (const float*)d_in[10];
    const float* Wd1   = (const float*)d_in[11];
    const float* bd1   = (const float*)d_in[12];
    const float* Wd2   = (const float*)d_in[13];
    const float* bd2   = (const float*)d_in[14];
    float* out = (float*)d_out;

    char* ws = (char*)d_ws;
    int*   offs   = (int*)(ws + OFF_OFFS);
    float* degf   = (float*)(ws + OFF_DEGF);
    float* invd   = (float*)(ws + OFF_INVD);
    int*   bucket = (int*)(ws + OFF_BUCKET);
    float* xs     = (float*)(ws + OFF_XS);
    float* he     = (float*)(ws + OFF_HE);
    float* hdT    = (float*)(ws + OFF_HDT);
    float* part   = (float*)(ws + OFF_PART);

    float* outMean = out + (size_t)kB * kIn;
    float* outLv   = outMean + (size_t)kB * kLat;

    gnn_k_pre<<<1, 1024, 0, stream>>>(ei, offs, bucket, degf, invd);
    gnn_k_conv<<<kB * (kN / 4), 256, 0, stream>>>(x, Wm, bm, offs, bucket, degf, invd, xs);

    if (ws_size >= WS_NEED) {
        gnn_k_enc<false><<<dim3(NKC, 2), 256, 0, stream>>>(xs, We1, part);
        gnn_k_encred<<<kB * kHid / 256, 256, 0, stream>>>(part, be1, he);
    } else {
        hipMemsetAsync(he, 0, (size_t)kB * kHid * 4, stream);
        gnn_k_enc<true><<<dim3(NKC, 2), 256, 0, stream>>>(xs, We1, he);
        gnn_k_hefin<<<(kB * kHid + 255) / 256, 256, 0, stream>>>(he, be1);
    }

    gnn_k_latdec1<<<kB, kHid, 0, stream>>>(he, Wmean, bmean, Wlv, blv, eps,
                                           Wd1, bd1, outMean, outLv, hdT);
    gnn_k_dec2<<<kIn / 128, 256, 0, stream>>>(hdT, Wd2, bd2, out);
}

// Round 6
// 624.595 us; speedup vs baseline: 1.9288x; 1.3914x over previous
//
#include <hip/hip_runtime.h>
#include <cstdint>
#include <cstddef>

// ---------------- problem constants ----------------
constexpr int kB   = 64;      // graphs
constexpr int kN   = 1000;    // nodes per graph
constexpr int kF   = 64;      // node features
constexpr int kE   = 32000;   // edges
constexpr int kIn  = 64000;   // N*F flattened
constexpr int kHid = 512;
constexpr int kLat = 128;
constexpr float kSlope = 0.01f;

constexpr int KC  = 256;           // encoder k-chunk
constexpr int NKC = kIn / KC;      // 250 chunks

// ---------------- workspace layout (bytes) ----------------
constexpr size_t OFF_OFFS   = 0;                                   // int[1001]
constexpr size_t OFF_DEGF   = 4096;                                // float[1000]
constexpr size_t OFF_INVD   = 8192;                                // float[1000]
constexpr size_t OFF_BUCKET = 12288;                               // int[32000]
constexpr size_t OFF_XS     = 140288;                              // float[64*64000]
constexpr size_t OFF_HE     = OFF_XS  + (size_t)kB * kIn  * 4;     // float[64*512]
constexpr size_t OFF_HDT    = OFF_HE  + (size_t)kB * kHid * 4;     // float[512*64]
constexpr size_t OFF_PART   = OFF_HDT + (size_t)kHid * kB * 4;     // float[250*64*512]
constexpr size_t WS_NEED    = OFF_PART + (size_t)NKC * kB * kHid * 4;

// ---------------- fused graph preprocessing (single block) ----------------
__global__ __launch_bounds__(1024) void gnn_k_pre(
    const int* __restrict__ ei, int* __restrict__ offs, int* __restrict__ bucket,
    float* __restrict__ degf, float* __restrict__ invd) {
    __shared__ int s_deg[kN];
    __shared__ int s_scan[1024];
    __shared__ int s_cur[kN];
    int t = threadIdx.x;
    if (t < kN) s_deg[t] = 0;
    __syncthreads();
    for (int e = t; e < kE; e += 1024) atomicAdd(&s_deg[ei[kE + e]], 1);
    __syncthreads();
    int v = (t < kN) ? s_deg[t] : 0;
    s_scan[t] = v;
    __syncthreads();
    for (int d = 1; d < 1024; d <<= 1) {
        int add = (t >= d) ? s_scan[t - d] : 0;
        __syncthreads();
        s_scan[t] += add;
        __syncthreads();
    }
    if (t < kN) {
        int excl = s_scan[t] - v;
        offs[t]  = excl;
        s_cur[t] = excl;
        degf[t]  = (float)v;
        invd[t]  = 1.0f / fmaxf((float)v, 1.0f);
    }
    if (t == kN - 1) offs[kN] = s_scan[t];
    __syncthreads();
    for (int e = t; e < kE; e += 1024) {
        int d = ei[kE + e];
        int pos = atomicAdd(&s_cur[d], 1);
        bucket[pos] = ei[e];           // src
    }
}

// ---------------- GeneralConv: aggregate + linear + skip + LeakyReLU ----------------
// 256 threads = 4 waves = 4 nodes. Wave matmul via readlane broadcast.
__global__ __launch_bounds__(256) void gnn_k_conv(
    const float* __restrict__ x, const float* __restrict__ Wm,
    const float* __restrict__ bm, const int* __restrict__ offs,
    const int* __restrict__ bucket, const float* __restrict__ degf,
    const float* __restrict__ invd, float* __restrict__ xs) {
    int blk  = blockIdx.x;
    int b    = blk / (kN / 4);
    int ng   = blk - b * (kN / 4);
    int wave = threadIdx.x >> 6;
    int f    = threadIdx.x & 63;
    int n    = ng * 4 + wave;
    const float* xb = x + (size_t)b * kIn;
    int beg = offs[n], end = offs[n + 1];
    float a0 = 0.f, a1 = 0.f;
    int i = beg;
    for (; i + 2 <= end; i += 2) {
        int s0 = bucket[i], s1 = bucket[i + 1];
        a0 += xb[s0 * kF + f];
        a1 += xb[s1 * kF + f];
    }
    if (i < end) a0 += xb[bucket[i] * kF + f];
    float acc = a0 + a1;
    float d0 = 0.f, d1 = 0.f, d2 = 0.f, d3 = 0.f;
    #pragma unroll
    for (int ff = 0; ff < kF; ff += 4) {
        d0 = fmaf(__shfl(acc, ff    ), Wm[(ff    ) * kF + f], d0);
        d1 = fmaf(__shfl(acc, ff + 1), Wm[(ff + 1) * kF + f], d1);
        d2 = fmaf(__shfl(acc, ff + 2), Wm[(ff + 2) * kF + f], d2);
        d3 = fmaf(__shfl(acc, ff + 3), Wm[(ff + 3) * kF + f], d3);
    }
    float dot = (d0 + d1) + (d2 + d3);
    float dg  = degf[n];
    float val = (dot + dg * bm[f]) * invd[n];
    float hv  = val + xb[n * kF + f];
    hv = hv >= 0.f ? hv : kSlope * hv;
    xs[(size_t)b * kIn + n * kF + f] = hv;
}

// ---------------- Encoder GEMM (LDS-staged, register-tiled, split-K) ----------------
// grid (NKC, 2), block 256. Block: [64m x 256n] over 256 k. Thread: 16m x 4n.
template <bool ATOMIC>
__global__ __launch_bounds__(256) void gnn_k_enc(
    const float* __restrict__ xs, const float* __restrict__ We1,
    float* __restrict__ out) {
    int c  = blockIdx.x;
    int by = blockIdx.y;
    int t  = threadIdx.x;
    int nl = t & 63;
    int mg = t >> 6;
    int k0 = c * KC;
    int cb = by * 256 + nl * 4;
    int m0 = mg * 16;

    __shared__ float s_x[kB][KC];          // 64 KB
    const float4* xs4 = (const float4*)xs;
    #pragma unroll
    for (int i = t; i < kB * (KC / 4); i += 256) {
        int m  = i >> 6;                   // KC/4 = 64 float4 per row
        int jw = i & 63;
        *(float4*)&s_x[m][jw * 4] = xs4[(size_t)m * (kIn / 4) + (k0 >> 2) + jw];
    }
    __syncthreads();

    float acc[16][4];
    #pragma unroll
    for (int mm = 0; mm < 16; ++mm)
        #pragma unroll
        for (int j = 0; j < 4; ++j) acc[mm][j] = 0.f;

    const float* wbase = We1 + (size_t)k0 * kHid + cb;
    for (int kk = 0; kk < KC; kk += 4) {
        const float* wk = wbase + (size_t)kk * kHid;
        float4 w0 = *(const float4*)(wk);
        float4 w1 = *(const float4*)(wk + kHid);
        float4 w2 = *(const float4*)(wk + 2 * kHid);
        float4 w3 = *(const float4*)(wk + 3 * kHid);
        #pragma unroll
        for (int mm = 0; mm < 16; ++mm) {
            float4 xv = *(const float4*)&s_x[m0 + mm][kk];   // wave-broadcast
            acc[mm][0] = fmaf(xv.x, w0.x, fmaf(xv.y, w1.x, fmaf(xv.z, w2.x, fmaf(xv.w, w3.x, acc[mm][0]))));
            acc[mm][1] = fmaf(xv.x, w0.y, fmaf(xv.y, w1.y, fmaf(xv.z, w2.y, fmaf(xv.w, w3.y, acc[mm][1]))));
            acc[mm][2] = fmaf(xv.x, w0.z, fmaf(xv.y, w1.z, fmaf(xv.z, w2.z, fmaf(xv.w, w3.z, acc[mm][2]))));
            acc[mm][3] = fmaf(xv.x, w0.w, fmaf(xv.y, w1.w, fmaf(xv.z, w2.w, fmaf(xv.w, w3.w, acc[mm][3]))));
        }
    }

    if (ATOMIC) {
        #pragma unroll
        for (int mm = 0; mm < 16; ++mm)
            #pragma unroll
            for (int j = 0; j < 4; ++j)
                atomicAdd(&out[(size_t)(m0 + mm) * kHid + cb + j], acc[mm][j]);
    } else {
        #pragma unroll
        for (int mm = 0; mm < 16; ++mm) {
            float4 v = make_float4(acc[mm][0], acc[mm][1], acc[mm][2], acc[mm][3]);
            *(float4*)&out[((size_t)c * kB + m0 + mm) * kHid + cb] = v;
        }
    }
}

// reduce partials + bias + ReLU
__global__ __launch_bounds__(256) void gnn_k_encred(
    const float* __restrict__ part, const float* __restrict__ be1,
    float* __restrict__ he) {
    int id = blockIdx.x * 256 + threadIdx.x;   // 32768
    int n = id & 511, m = id >> 9;
    float s0 = 0.f, s1 = 0.f, s2 = 0.f, s3 = 0.f;
    const float* p = part + (size_t)m * kHid + n;
    #pragma unroll 2
    for (int c = 0; c < NKC; c += 4) {
        s0 += p[(size_t)(c    ) * kB * kHid];
        s1 += p[(size_t)(c + 1) * kB * kHid];
        s2 += p[(size_t)(c + 2) * kB * kHid];
        s3 += p[(size_t)(c + 3) * kB * kHid];
    }
    float s = (s0 + s1) + (s2 + s3) + be1[n];
    he[id] = fmaxf(s, 0.f);
}

__global__ void gnn_k_hefin(float* __restrict__ he, const float* __restrict__ be1) {
    int i = blockIdx.x * 256 + threadIdx.x;
    if (i < kB * kHid) {
        float v = he[i] + be1[i & 511];
        he[i] = v > 0.f ? v : 0.f;
    }
}

// ---------------- fused latent + decoder layer 1 ----------------
__global__ __launch_bounds__(512) void gnn_k_latdec1(
    const float* __restrict__ he, const float* __restrict__ Wmean,
    const float* __restrict__ bmean, const float* __restrict__ Wlv,
    const float* __restrict__ blv, const float* __restrict__ eps,
    const float* __restrict__ Wd1, const float* __restrict__ bd1,
    float* __restrict__ outMean, float* __restrict__ outLv,
    float* __restrict__ hdT) {
    int b = blockIdx.x;
    int t = threadIdx.x;
    __shared__ float s_he[kHid];
    __shared__ float s_z[kLat];
    s_he[t] = he[(size_t)b * kHid + t];
    __syncthreads();
    if (t < kLat) {
        float dm = bmean[t], dv = blv[t];
        float dm1 = 0.f, dv1 = 0.f;
        #pragma unroll 4
        for (int k = 0; k < kHid; k += 2) {
            float h0 = s_he[k], h1 = s_he[k + 1];
            dm  = fmaf(h0, Wmean[(size_t)k * kLat + t], dm);
            dm1 = fmaf(h1, Wmean[(size_t)(k + 1) * kLat + t], dm1);
            dv  = fmaf(h0, Wlv[(size_t)k * kLat + t], dv);
            dv1 = fmaf(h1, Wlv[(size_t)(k + 1) * kLat + t], dv1);
        }
        dm += dm1; dv += dv1;
        outMean[b * kLat + t] = dm;
        outLv[b * kLat + t]   = dv;
        s_z[t] = fmaf(expf(0.5f * dv), eps[b * kLat + t], dm);
    }
    __syncthreads();
    float acc = bd1[t];
    float acc1 = 0.f;
    #pragma unroll 4
    for (int k = 0; k < kLat; k += 2) {
        acc  = fmaf(s_z[k],     Wd1[(size_t)k * kHid + t], acc);
        acc1 = fmaf(s_z[k + 1], Wd1[(size_t)(k + 1) * kHid + t], acc1);
    }
    acc += acc1;
    hdT[(size_t)t * kB + b] = fmaxf(acc, 0.f);   // transposed: hdT[k][m]
}

// ---------------- decoder GEMM (LDS-staged, register-tiled) ----------------
// out = sigmoid(hd[64,512] @ Wd2[512,64000] + b). Block: 512 thr, tile [64m x 128n],
// K staged in 4 LDS chunks of 128 (32 KB -> 2 blocks/CU -> 16 waves/CU).
// Thread: 4m x 4n. Per k: 1 coalesced float4 W + 1 broadcast ds_read_b128 + 16 FMA.
constexpr int DKC = 128;    // dec2 k-chunk
__global__ __launch_bounds__(512) void gnn_k_dec2(
    const float* __restrict__ hdT, const float* __restrict__ Wd2,
    const float* __restrict__ bd2, float* __restrict__ out) {
    int t  = threadIdx.x;
    int ng = t & 31;          // 32 n-groups x 4 cols = 128 cols
    int mg = t >> 5;          // 16 m-groups x 4 rows = 64 rows
    int n0 = blockIdx.x * 128 + ng * 4;
    int m0 = mg * 4;

    __shared__ float s_hd[DKC][kB];       // 32 KB: [k][m], same layout as hdT chunk

    float acc[4][4];
    #pragma unroll
    for (int i = 0; i < 4; ++i)
        #pragma unroll
        for (int j = 0; j < 4; ++j) acc[i][j] = 0.f;

    for (int kc = 0; kc < kHid; kc += DKC) {
        // stage hdT chunk: contiguous 8192 floats = 2048 float4
        const float4* src = (const float4*)(hdT + (size_t)kc * kB);
        float4* dst = (float4*)&s_hd[0][0];
        #pragma unroll
        for (int r = 0; r < 4; ++r) dst[t + 512 * r] = src[t + 512 * r];
        __syncthreads();

        const float* wp = Wd2 + (size_t)kc * kIn + n0;
        #pragma unroll 4
        for (int k = 0; k < DKC; ++k) {
            float4 w = *(const float4*)(wp + (size_t)k * kIn);
            float4 h = *(const float4*)&s_hd[k][m0];       // 16B broadcast read
            acc[0][0] = fmaf(h.x, w.x, acc[0][0]);
            acc[0][1] = fmaf(h.x, w.y, acc[0][1]);
            acc[0][2] = fmaf(h.x, w.z, acc[0][2]);
            acc[0][3] = fmaf(h.x, w.w, acc[0][3]);
            acc[1][0] = fmaf(h.y, w.x, acc[1][0]);
            acc[1][1] = fmaf(h.y, w.y, acc[1][1]);
            acc[1][2] = fmaf(h.y, w.z, acc[1][2]);
            acc[1][3] = fmaf(h.y, w.w, acc[1][3]);
            acc[2][0] = fmaf(h.z, w.x, acc[2][0]);
            acc[2][1] = fmaf(h.z, w.y, acc[2][1]);
            acc[2][2] = fmaf(h.z, w.z, acc[2][2]);
            acc[2][3] = fmaf(h.z, w.w, acc[2][3]);
            acc[3][0] = fmaf(h.w, w.x, acc[3][0]);
            acc[3][1] = fmaf(h.w, w.y, acc[3][1]);
            acc[3][2] = fmaf(h.w, w.z, acc[3][2]);
            acc[3][3] = fmaf(h.w, w.w, acc[3][3]);
        }
        __syncthreads();
    }

    float4 bb = *(const float4*)(bd2 + n0);
    #pragma unroll
    for (int i = 0; i < 4; ++i) {
        float4 v;
        v.x = 1.f / (1.f + expf(-(acc[i][0] + bb.x)));
        v.y = 1.f / (1.f + expf(-(acc[i][1] + bb.y)));
        v.z = 1.f / (1.f + expf(-(acc[i][2] + bb.z)));
        v.w = 1.f / (1.f + expf(-(acc[i][3] + bb.w)));
        *(float4*)(out + (size_t)(m0 + i) * kIn + n0) = v;
    }
}

// ---------------- launcher ----------------
extern "C" void kernel_launch(void* const* d_in, const int* in_sizes, int n_in,
                              void* d_out, int out_size, void* d_ws, size_t ws_size,
                              hipStream_t stream) {
    const float* x     = (const float*)d_in[0];
    const int*   ei    = (const int*)d_in[1];
    const float* eps   = (const float*)d_in[2];
    const float* Wm    = (const float*)d_in[3];
    const float* bm    = (const float*)d_in[4];
    const float* We1   = (const float*)d_in[5];
    const float* be1   = (const float*)d_in[6];
    const float* Wmean = (const float*)d_in[7];
    const float* bmean = (const float*)d_in[8];
    const float* Wlv   = (const float*)d_in[9];
    const float* blv   = (const float*)d_in[10];
    const float* Wd1   = (const float*)d_in[11];
    const float* bd1   = (const float*)d_in[12];
    const float* Wd2   = (const float*)d_in[13];
    const float* bd2   = (const float*)d_in[14];
    float* out = (float*)d_out;

    char* ws = (char*)d_ws;
    int*   offs   = (int*)(ws + OFF_OFFS);
    float* degf   = (float*)(ws + OFF_DEGF);
    float* invd   = (float*)(ws + OFF_INVD);
    int*   bucket = (int*)(ws + OFF_BUCKET);
    float* xs     = (float*)(ws + OFF_XS);
    float* he     = (float*)(ws + OFF_HE);
    float* hdT    = (float*)(ws + OFF_HDT);
    float* part   = (float*)(ws + OFF_PART);

    float* outMean = out + (size_t)kB * kIn;
    float* outLv   = outMean + (size_t)kB * kLat;

    gnn_k_pre<<<1, 1024, 0, stream>>>(ei, offs, bucket, degf, invd);
    gnn_k_conv<<<kB * (kN / 4), 256, 0, stream>>>(x, Wm, bm, offs, bucket, degf, invd, xs);

    if (ws_size >= WS_NEED) {
        gnn_k_enc<false><<<dim3(NKC, 2), 256, 0, stream>>>(xs, We1, part);
        gnn_k_encred<<<kB * kHid / 256, 256, 0, stream>>>(part, be1, he);
    } else {
        hipMemsetAsync(he, 0, (size_t)kB * kHid * 4, stream);
        gnn_k_enc<true><<<dim3(NKC, 2), 256, 0, stream>>>(xs, We1, he);
        gnn_k_hefin<<<(kB * kHid + 255) / 256, 256, 0, stream>>>(he, be1);
    }

    gnn_k_latdec1<<<kB, kHid, 0, stream>>>(he, Wmean, bmean, Wlv, blv, eps,
                                           Wd1, bd1, outMean, outLv, hdT);
    gnn_k_dec2<<<kIn / 128, 512, 0, stream>>>(hdT, Wd2, bd2, out);
}

// Round 7
// 568.170 us; speedup vs baseline: 2.1203x; 1.0993x over previous
//
#include <hip/hip_runtime.h>
#include <cstdint>
#include <cstddef>

// ---------------- problem constants ----------------
constexpr int kB   = 64;      // graphs
constexpr int kN   = 1000;    // nodes per graph
constexpr int kF   = 64;      // node features
constexpr int kE   = 32000;   // edges
constexpr int kIn  = 64000;   // N*F flattened
constexpr int kHid = 512;
constexpr int kLat = 128;
constexpr float kSlope = 0.01f;

constexpr int KC  = 256;           // encoder k-chunk
constexpr int NKC = kIn / KC;      // 250 chunks

// ---------------- workspace layout (bytes) ----------------
constexpr size_t OFF_OFFS   = 0;                                   // int[1001]
constexpr size_t OFF_DEGF   = 4096;                                // float[1000]
constexpr size_t OFF_INVD   = 8192;                                // float[1000]
constexpr size_t OFF_BUCKET = 12288;                               // int[32000]
constexpr size_t OFF_XS     = 140288;                              // float[64*64000]
constexpr size_t OFF_HE     = OFF_XS  + (size_t)kB * kIn  * 4;     // float[64*512]
constexpr size_t OFF_HDT    = OFF_HE  + (size_t)kB * kHid * 4;     // float[512*64]
constexpr size_t OFF_PART   = OFF_HDT + (size_t)kHid * kB * 4;     // float[250*64*512]
constexpr size_t WS_NEED    = OFF_PART + (size_t)NKC * kB * kHid * 4;

// ---------------- fused graph preprocessing (single block) ----------------
__global__ __launch_bounds__(1024) void gnn_k_pre(
    const int* __restrict__ ei, int* __restrict__ offs, int* __restrict__ bucket,
    float* __restrict__ degf, float* __restrict__ invd) {
    __shared__ int s_deg[kN];
    __shared__ int s_scan[1024];
    __shared__ int s_cur[kN];
    int t = threadIdx.x;
    if (t < kN) s_deg[t] = 0;
    __syncthreads();
    for (int e = t; e < kE; e += 1024) atomicAdd(&s_deg[ei[kE + e]], 1);
    __syncthreads();
    int v = (t < kN) ? s_deg[t] : 0;
    s_scan[t] = v;
    __syncthreads();
    for (int d = 1; d < 1024; d <<= 1) {
        int add = (t >= d) ? s_scan[t - d] : 0;
        __syncthreads();
        s_scan[t] += add;
        __syncthreads();
    }
    if (t < kN) {
        int excl = s_scan[t] - v;
        offs[t]  = excl;
        s_cur[t] = excl;
        degf[t]  = (float)v;
        invd[t]  = 1.0f / fmaxf((float)v, 1.0f);
    }
    if (t == kN - 1) offs[kN] = s_scan[t];
    __syncthreads();
    for (int e = t; e < kE; e += 1024) {
        int d = ei[kE + e];
        int pos = atomicAdd(&s_cur[d], 1);
        bucket[pos] = ei[e];           // src
    }
}

// ---------------- GeneralConv: aggregate + linear + skip + LeakyReLU ----------------
// Wave = (graph-pair, node): lane=f. 4-way edge unroll x 2 graphs = 8 loads in
// flight. XCD-bijective swizzle: each XCD owns 4 contiguous b-pairs (2MB < 4MB L2).
__global__ __launch_bounds__(256) void gnn_k_conv(
    const float* __restrict__ x, const float* __restrict__ Wm,
    const float* __restrict__ bm, const int* __restrict__ offs,
    const int* __restrict__ bucket, const float* __restrict__ degf,
    const float* __restrict__ invd, float* __restrict__ xs) {
    // nwg = 8000 (divisible by 8): wg = (bid%8)*1000 + bid/8  (bijective)
    int bid = blockIdx.x;
    int wg  = (bid & 7) * 1000 + (bid >> 3);
    int bp  = wg / (kN / 4);          // 0..31 graph pair
    int ng  = wg - bp * (kN / 4);     // 0..249
    int wave = threadIdx.x >> 6;
    int f    = threadIdx.x & 63;
    int n    = ng * 4 + wave;
    int b0   = bp * 2;
    const float* xb0 = x + (size_t)b0 * kIn;
    const float* xb1 = xb0 + kIn;
    int beg = offs[n], end = offs[n + 1];
    float p0 = 0.f, p1 = 0.f, q0 = 0.f, q1 = 0.f;
    float r0 = 0.f, r1 = 0.f, u0 = 0.f, u1 = 0.f;
    int i = beg;
    for (; i + 4 <= end; i += 4) {        // 8 row-loads in flight
        int i0 = bucket[i]     * kF + f;
        int i1 = bucket[i + 1] * kF + f;
        int i2 = bucket[i + 2] * kF + f;
        int i3 = bucket[i + 3] * kF + f;
        p0 += xb0[i0]; p1 += xb1[i0];
        q0 += xb0[i1]; q1 += xb1[i1];
        r0 += xb0[i2]; r1 += xb1[i2];
        u0 += xb0[i3]; u1 += xb1[i3];
    }
    for (; i < end; ++i) {
        int i0 = bucket[i] * kF + f;
        p0 += xb0[i0]; p1 += xb1[i0];
    }
    float acc0 = (p0 + q0) + (r0 + u0);
    float acc1 = (p1 + q1) + (r1 + u1);
    // dot[f] = sum_ff acc(lane ff) * Wm[ff][f], both graphs, 4 chains each
    float d00 = 0.f, d01 = 0.f, d02 = 0.f, d03 = 0.f;
    float d10 = 0.f, d11 = 0.f, d12 = 0.f, d13 = 0.f;
    #pragma unroll
    for (int ff = 0; ff < kF; ff += 4) {
        float w0 = Wm[(ff    ) * kF + f];
        float w1 = Wm[(ff + 1) * kF + f];
        float w2 = Wm[(ff + 2) * kF + f];
        float w3 = Wm[(ff + 3) * kF + f];
        d00 = fmaf(__shfl(acc0, ff    ), w0, d00);
        d01 = fmaf(__shfl(acc0, ff + 1), w1, d01);
        d02 = fmaf(__shfl(acc0, ff + 2), w2, d02);
        d03 = fmaf(__shfl(acc0, ff + 3), w3, d03);
        d10 = fmaf(__shfl(acc1, ff    ), w0, d10);
        d11 = fmaf(__shfl(acc1, ff + 1), w1, d11);
        d12 = fmaf(__shfl(acc1, ff + 2), w2, d12);
        d13 = fmaf(__shfl(acc1, ff + 3), w3, d13);
    }
    float dot0 = (d00 + d01) + (d02 + d03);
    float dot1 = (d10 + d11) + (d12 + d13);
    float dg  = degf[n];
    float iv  = invd[n];
    float bmf = bm[f];
    float v0 = (dot0 + dg * bmf) * iv + xb0[n * kF + f];
    float v1 = (dot1 + dg * bmf) * iv + xb1[n * kF + f];
    v0 = v0 >= 0.f ? v0 : kSlope * v0;
    v1 = v1 >= 0.f ? v1 : kSlope * v1;
    xs[(size_t)b0 * kIn + n * kF + f] = v0;
    xs[(size_t)(b0 + 1) * kIn + n * kF + f] = v1;
}

// ---------------- Encoder GEMM (LDS-staged, register-tiled, split-K) ----------------
// grid (NKC, 2), block 512 (8 waves -> 16 waves/CU at 64KB LDS).
// Block: [64m x 256n] over 256 k. Thread: 8m x 4n. Wave-uniform LDS rows
// (mg = wave id) -> broadcast ds_read_b128, conflict-free; W float4 coalesced.
template <bool ATOMIC>
__global__ __launch_bounds__(512) void gnn_k_enc(
    const float* __restrict__ xs, const float* __restrict__ We1,
    float* __restrict__ out) {
    int c  = blockIdx.x;
    int by = blockIdx.y;
    int t  = threadIdx.x;
    int nl = t & 63;
    int mg = t >> 6;          // wave id 0..7
    int k0 = c * KC;
    int cb = by * 256 + nl * 4;
    int m0 = mg * 8;

    __shared__ float s_x[kB][KC];          // 64 KB
    const float4* xs4 = (const float4*)xs;
    #pragma unroll
    for (int i = t; i < kB * (KC / 4); i += 512) {   // 4096 float4, 8 iters
        int m  = i >> 6;
        int jw = i & 63;
        *(float4*)&s_x[m][jw * 4] = xs4[(size_t)m * (kIn / 4) + (k0 >> 2) + jw];
    }
    __syncthreads();

    float acc[8][4];
    #pragma unroll
    for (int mm = 0; mm < 8; ++mm)
        #pragma unroll
        for (int j = 0; j < 4; ++j) acc[mm][j] = 0.f;

    const float* wbase = We1 + (size_t)k0 * kHid + cb;
    for (int kk = 0; kk < KC; kk += 4) {
        const float* wk = wbase + (size_t)kk * kHid;
        float4 w0 = *(const float4*)(wk);
        float4 w1 = *(const float4*)(wk + kHid);
        float4 w2 = *(const float4*)(wk + 2 * kHid);
        float4 w3 = *(const float4*)(wk + 3 * kHid);
        #pragma unroll
        for (int mm = 0; mm < 8; ++mm) {
            float4 xv = *(const float4*)&s_x[m0 + mm][kk];   // wave-broadcast
            acc[mm][0] = fmaf(xv.x, w0.x, fmaf(xv.y, w1.x, fmaf(xv.z, w2.x, fmaf(xv.w, w3.x, acc[mm][0]))));
            acc[mm][1] = fmaf(xv.x, w0.y, fmaf(xv.y, w1.y, fmaf(xv.z, w2.y, fmaf(xv.w, w3.y, acc[mm][1]))));
            acc[mm][2] = fmaf(xv.x, w0.z, fmaf(xv.y, w1.z, fmaf(xv.z, w2.z, fmaf(xv.w, w3.z, acc[mm][2]))));
            acc[mm][3] = fmaf(xv.x, w0.w, fmaf(xv.y, w1.w, fmaf(xv.z, w2.w, fmaf(xv.w, w3.w, acc[mm][3]))));
        }
    }

    if (ATOMIC) {
        #pragma unroll
        for (int mm = 0; mm < 8; ++mm)
            #pragma unroll
            for (int j = 0; j < 4; ++j)
                atomicAdd(&out[(size_t)(m0 + mm) * kHid + cb + j], acc[mm][j]);
    } else {
        #pragma unroll
        for (int mm = 0; mm < 8; ++mm) {
            float4 v = make_float4(acc[mm][0], acc[mm][1], acc[mm][2], acc[mm][3]);
            *(float4*)&out[((size_t)c * kB + m0 + mm) * kHid + cb] = v;
        }
    }
}

__global__ void gnn_k_hefin(float* __restrict__ he, const float* __restrict__ be1) {
    int i = blockIdx.x * 256 + threadIdx.x;
    if (i < kB * kHid) {
        float v = he[i] + be1[i & 511];
        he[i] = v > 0.f ? v : 0.f;
    }
}

// ---------------- fused (split-K reduce) + latent + decoder layer 1 ----------------
// RED: hesrc = part[250][64][512]; reduce + bias + ReLU inline (encred folded in).
// else: hesrc = he (already biased+ReLU'd by hefin, atomic fallback path).
template <bool RED>
__global__ __launch_bounds__(512) void gnn_k_latdec1(
    const float* __restrict__ hesrc, const float* __restrict__ be1,
    const float* __restrict__ Wmean, const float* __restrict__ bmean,
    const float* __restrict__ Wlv, const float* __restrict__ blv,
    const float* __restrict__ eps,
    const float* __restrict__ Wd1, const float* __restrict__ bd1,
    float* __restrict__ outMean, float* __restrict__ outLv,
    float* __restrict__ hdT) {
    int b = blockIdx.x;
    int t = threadIdx.x;
    __shared__ float s_he[kHid];
    __shared__ float s_z[kLat];
    if (RED) {
        const float* p = hesrc + (size_t)b * kHid + t;
        float s0 = 0.f, s1 = 0.f, s2 = 0.f, s3 = 0.f;
        int c = 0;
        for (; c + 4 <= NKC; c += 4) {
            s0 += p[(size_t)(c    ) * kB * kHid];
            s1 += p[(size_t)(c + 1) * kB * kHid];
            s2 += p[(size_t)(c + 2) * kB * kHid];
            s3 += p[(size_t)(c + 3) * kB * kHid];
        }
        for (; c < NKC; ++c) s0 += p[(size_t)c * kB * kHid];
        float s = (s0 + s1) + (s2 + s3) + be1[t];
        s_he[t] = fmaxf(s, 0.f);
    } else {
        s_he[t] = hesrc[(size_t)b * kHid + t];
    }
    __syncthreads();
    if (t < kLat) {
        float dm = bmean[t], dv = blv[t];
        float dm1 = 0.f, dv1 = 0.f;
        #pragma unroll 4
        for (int k = 0; k < kHid; k += 2) {
            float h0 = s_he[k], h1 = s_he[k + 1];
            dm  = fmaf(h0, Wmean[(size_t)k * kLat + t], dm);
            dm1 = fmaf(h1, Wmean[(size_t)(k + 1) * kLat + t], dm1);
            dv  = fmaf(h0, Wlv[(size_t)k * kLat + t], dv);
            dv1 = fmaf(h1, Wlv[(size_t)(k + 1) * kLat + t], dv1);
        }
        dm += dm1; dv += dv1;
        outMean[b * kLat + t] = dm;
        outLv[b * kLat + t]   = dv;
        s_z[t] = fmaf(expf(0.5f * dv), eps[b * kLat + t], dm);
    }
    __syncthreads();
    float acc = bd1[t];
    float acc1 = 0.f;
    #pragma unroll 4
    for (int k = 0; k < kLat; k += 2) {
        acc  = fmaf(s_z[k],     Wd1[(size_t)k * kHid + t], acc);
        acc1 = fmaf(s_z[k + 1], Wd1[(size_t)(k + 1) * kHid + t], acc1);
    }
    acc += acc1;
    hdT[(size_t)t * kB + b] = fmaxf(acc, 0.f);   // transposed: hdT[k][m]
}

// ---------------- decoder GEMM (LDS-staged, register-tiled) ----------------
constexpr int DKC = 128;    // dec2 k-chunk
__global__ __launch_bounds__(512) void gnn_k_dec2(
    const float* __restrict__ hdT, const float* __restrict__ Wd2,
    const float* __restrict__ bd2, float* __restrict__ out) {
    int t  = threadIdx.x;
    int ng = t & 31;          // 32 n-groups x 4 cols = 128 cols
    int mg = t >> 5;          // 16 m-groups x 4 rows = 64 rows
    int n0 = blockIdx.x * 128 + ng * 4;
    int m0 = mg * 4;

    __shared__ float s_hd[DKC][kB];       // 32 KB

    float acc[4][4];
    #pragma unroll
    for (int i = 0; i < 4; ++i)
        #pragma unroll
        for (int j = 0; j < 4; ++j) acc[i][j] = 0.f;

    for (int kc = 0; kc < kHid; kc += DKC) {
        const float4* src = (const float4*)(hdT + (size_t)kc * kB);
        float4* dst = (float4*)&s_hd[0][0];
        #pragma unroll
        for (int r = 0; r < 4; ++r) dst[t + 512 * r] = src[t + 512 * r];
        __syncthreads();

        const float* wp = Wd2 + (size_t)kc * kIn + n0;
        #pragma unroll 4
        for (int k = 0; k < DKC; ++k) {
            float4 w = *(const float4*)(wp + (size_t)k * kIn);
            float4 h = *(const float4*)&s_hd[k][m0];       // broadcast
            acc[0][0] = fmaf(h.x, w.x, acc[0][0]);
            acc[0][1] = fmaf(h.x, w.y, acc[0][1]);
            acc[0][2] = fmaf(h.x, w.z, acc[0][2]);
            acc[0][3] = fmaf(h.x, w.w, acc[0][3]);
            acc[1][0] = fmaf(h.y, w.x, acc[1][0]);
            acc[1][1] = fmaf(h.y, w.y, acc[1][1]);
            acc[1][2] = fmaf(h.y, w.z, acc[1][2]);
            acc[1][3] = fmaf(h.y, w.w, acc[1][3]);
            acc[2][0] = fmaf(h.z, w.x, acc[2][0]);
            acc[2][1] = fmaf(h.z, w.y, acc[2][1]);
            acc[2][2] = fmaf(h.z, w.z, acc[2][2]);
            acc[2][3] = fmaf(h.z, w.w, acc[2][3]);
            acc[3][0] = fmaf(h.w, w.x, acc[3][0]);
            acc[3][1] = fmaf(h.w, w.y, acc[3][1]);
            acc[3][2] = fmaf(h.w, w.z, acc[3][2]);
            acc[3][3] = fmaf(h.w, w.w, acc[3][3]);
        }
        __syncthreads();
    }

    float4 bb = *(const float4*)(bd2 + n0);
    #pragma unroll
    for (int i = 0; i < 4; ++i) {
        float4 v;
        v.x = 1.f / (1.f + expf(-(acc[i][0] + bb.x)));
        v.y = 1.f / (1.f + expf(-(acc[i][1] + bb.y)));
        v.z = 1.f / (1.f + expf(-(acc[i][2] + bb.z)));
        v.w = 1.f / (1.f + expf(-(acc[i][3] + bb.w)));
        *(float4*)(out + (size_t)(m0 + i) * kIn + n0) = v;
    }
}

// ---------------- launcher ----------------
extern "C" void kernel_launch(void* const* d_in, const int* in_sizes, int n_in,
                              void* d_out, int out_size, void* d_ws, size_t ws_size,
                              hipStream_t stream) {
    const float* x     = (const float*)d_in[0];
    const int*   ei    = (const int*)d_in[1];
    const float* eps   = (const float*)d_in[2];
    const float* Wm    = (const float*)d_in[3];
    const float* bm    = (const float*)d_in[4];
    const float* We1   = (const float*)d_in[5];
    const float* be1   = (const float*)d_in[6];
    const float* Wmean = (const float*)d_in[7];
    const float* bmean = (const float*)d_in[8];
    const float* Wlv   = (const float*)d_in[9];
    const float* blv   = (const float*)d_in[10];
    const float* Wd1   = (const float*)d_in[11];
    const float* bd1   = (const float*)d_in[12];
    const float* Wd2   = (const float*)d_in[13];
    const float* bd2   = (const float*)d_in[14];
    float* out = (float*)d_out;

    char* ws = (char*)d_ws;
    int*   offs   = (int*)(ws + OFF_OFFS);
    float* degf   = (float*)(ws + OFF_DEGF);
    float* invd   = (float*)(ws + OFF_INVD);
    int*   bucket = (int*)(ws + OFF_BUCKET);
    float* xs     = (float*)(ws + OFF_XS);
    float* he     = (float*)(ws + OFF_HE);
    float* hdT    = (float*)(ws + OFF_HDT);
    float* part   = (float*)(ws + OFF_PART);

    float* outMean = out + (size_t)kB * kIn;
    float* outLv   = outMean + (size_t)kB * kLat;

    gnn_k_pre<<<1, 1024, 0, stream>>>(ei, offs, bucket, degf, invd);
    gnn_k_conv<<<(kB / 2) * (kN / 4), 256, 0, stream>>>(x, Wm, bm, offs, bucket,
                                                        degf, invd, xs);

    if (ws_size >= WS_NEED) {
        gnn_k_enc<false><<<dim3(NKC, 2), 512, 0, stream>>>(xs, We1, part);
        gnn_k_latdec1<true><<<kB, kHid, 0, stream>>>(part, be1, Wmean, bmean, Wlv,
                                                     blv, eps, Wd1, bd1,
                                                     outMean, outLv, hdT);
    } else {
        hipMemsetAsync(he, 0, (size_t)kB * kHid * 4, stream);
        gnn_k_enc<true><<<dim3(NKC, 2), 512, 0, stream>>>(xs, We1, he);
        gnn_k_hefin<<<(kB * kHid + 255) / 256, 256, 0, stream>>>(he, be1);
        gnn_k_latdec1<false><<<kB, kHid, 0, stream>>>(he, be1, Wmean, bmean, Wlv,
                                                      blv, eps, Wd1, bd1,
                                                      outMean, outLv, hdT);
    }

    gnn_k_dec2<<<kIn / 128, 512, 0, stream>>>(hdT, Wd2, bd2, out);
}